// Round 1
// baseline (664.947 us; speedup 1.0000x reference)
//
#include <hip/hip_runtime.h>
#include <cstddef>

#define N_ 4
#define D_ 16
#define H_ 128
#define W_ 128
#define K_ 24
#define L_ 6
#define NTAP_A 13
#define NTAP_B 14

// workspace layout (float offsets)
#define OFF_Q   0u
#define OFF_TGT 1048576u
#define OFF_H0  2097152u
#define OFF_H1  27262976u
#define OFF_W0P 52428800u
#define OFF_W1P 52429312u
#define OFF_W2P 52437376u
// total = 52,445,440 floats = ~200.1 MiB

// ---------------------------------------------------------------- pack weights
__global__ void pack_weights_k(const float* __restrict__ w0,
                               const float* __restrict__ w1,
                               const float* __restrict__ w2,
                               float* __restrict__ w0p,
                               float* __restrict__ w1p,
                               float* __restrict__ w2p) {
  int tid = threadIdx.x;
  // w0: [24][1][27] -> w0p[t][co], t<13 (mask A: idx < 13)
  for (int i = tid; i < NTAP_A * K_; i += 256) {
    int co = i % K_;
    int t  = i / K_;
    w0p[t * K_ + co] = w0[co * 27 + t];
  }
  // w1/w2: [co=24][ci=24][27] -> wp[ci][t][co], t<14 (mask B: idx <= 13)
  for (int i = tid; i < K_ * NTAP_B * K_; i += 256) {
    int co = i % K_;
    int t  = (i / K_) % NTAP_B;
    int ci = i / (K_ * NTAP_B);
    float a = w1[(co * K_ + ci) * 27 + t];
    float b = w2[(co * K_ + ci) * 27 + t];
    w1p[i] = a;
    w2p[i] = b;
  }
}

// ---------------------------------------------------------------- quantize
__global__ __launch_bounds__(256) void quantize_k(
    const float* __restrict__ x, const float* __restrict__ centers,
    float* __restrict__ qbar_out, float* __restrict__ q,
    int* __restrict__ tgt) {
  int idx = blockIdx.x * 256 + threadIdx.x;  // over [n][c][h][w]
  int w = idx & 127;
  int h = (idx >> 7) & 127;
  int c = (idx >> 14) & 15;
  int n = idx >> 18;

  float cs[L_];
#pragma unroll
  for (int l = 0; l < L_; ++l) cs[l] = centers[l];

  int xi = ((n * H_ + h) * W_ + w) * D_ + c;  // NHWC
  float xv = x[xi];

  float dv[L_];
  float dmin = 3.4e38f;
  int sym = 0;
#pragma unroll
  for (int l = 0; l < L_; ++l) {
    float df = xv - cs[l];
    float d = df * df;
    dv[l] = d;
    if (d < dmin) { dmin = d; sym = l; }
  }
  // softmax(-d) (SIGMA=1), max(-d) = -dmin
  float e[L_];
  float s = 0.f;
#pragma unroll
  for (int l = 0; l < L_; ++l) {
    e[l] = expf(dmin - dv[l]);
    s += e[l];
  }
  float qsoft = 0.f;
#pragma unroll
  for (int l = 0; l < L_; ++l) qsoft += (e[l] / s) * cs[l];

  float qhard = cs[sym];
  float qb = qsoft + (qhard - qsoft);  // forward == qhard up to rounding, match ref ops

  qbar_out[xi] = qb;    // NHWC output (first tuple element)
  q[idx] = qb;          // [n][c(depth)][h][w] for the conv stack
  tgt[idx] = sym;
}

// ---------------------------------------------------------------- conv0 (1 -> 24, 13 taps, pad = centers[0])
__global__ __launch_bounds__(256) void conv0_k(
    const float* __restrict__ q, const float* __restrict__ w0p,
    const float* __restrict__ b0, const float* __restrict__ centers,
    float* __restrict__ h0) {
  __shared__ float sw[NTAP_A * K_];
  __shared__ float sb[K_];
  for (int i = threadIdx.x; i < NTAP_A * K_; i += 256) sw[i] = w0p[i];
  if (threadIdx.x < K_) sb[threadIdx.x] = b0[threadIdx.x];
  __syncthreads();

  float pv = centers[0];

  int blk = blockIdx.x;  // 4096 = 64 h-pairs * 16 d * 4 n
  int h2 = blk & 63;
  int d = (blk >> 6) & 15;
  int n = blk >> 10;
  int w = threadIdx.x & 127;
  int h = (h2 << 1) | (threadIdx.x >> 7);

  float acc[K_];
#pragma unroll
  for (int i = 0; i < K_; ++i) acc[i] = sb[i];

  const float* base = q + ((n * D_ + d) * H_ + h) * W_ + w;

#pragma unroll 1
  for (int t = 0; t < NTAP_A; ++t) {
    int dz = t / 9 - 1;
    int r = t % 9;
    int dy = r / 3 - 1;
    int dx = r % 3 - 1;
    int hh = h + dy, ww = w + dx, dd = d + dz;
    bool ok = (dd >= 0) && ((unsigned)hh < H_) && ((unsigned)ww < W_);
    float xv = ok ? base[(dz * H_ + dy) * W_ + dx] : pv;
    const float* wr = sw + t * K_;
#pragma unroll
    for (int co = 0; co < K_; ++co) acc[co] = fmaf(xv, wr[co], acc[co]);
  }

  float* dst = h0 + (size_t)(((n * D_ + d) * H_ + h) * W_ + w) * K_;
#pragma unroll
  for (int i = 0; i < K_; i += 4) {
    float4 v = make_float4(fmaxf(acc[i], 0.f), fmaxf(acc[i + 1], 0.f),
                           fmaxf(acc[i + 2], 0.f), fmaxf(acc[i + 3], 0.f));
    *(float4*)(dst + i) = v;
  }
}

// ---------------------------------------------------------------- 24->24 masked-B conv accumulate (14 taps)
__device__ __forceinline__ void conv14_acc(const float* __restrict__ src,
                                           const float* sw, const float* sb,
                                           int n, int d, int h, int w,
                                           float acc[K_]) {
#pragma unroll
  for (int i = 0; i < K_; ++i) acc[i] = sb[i];

  const float* base = src + (size_t)(((n * D_ + d) * H_ + h) * W_ + w) * K_;

#pragma unroll 1
  for (int t = 0; t < NTAP_B; ++t) {
    int dz = t / 9 - 1;
    int r = t % 9;
    int dy = r / 3 - 1;
    int dx = r % 3 - 1;
    int hh = h + dy, ww = w + dx, dd = d + dz;
    bool ok = (dd >= 0) && ((unsigned)hh < H_) && ((unsigned)ww < W_);
    const float4* p =
        (const float4*)(base + (ptrdiff_t)((dz * H_ + dy) * W_ + dx) * K_);
    float xx[K_];
    if (ok) {
#pragma unroll
      for (int i = 0; i < 6; ++i) {
        float4 v = p[i];
        xx[4 * i] = v.x; xx[4 * i + 1] = v.y; xx[4 * i + 2] = v.z; xx[4 * i + 3] = v.w;
      }
    } else {
#pragma unroll
      for (int i = 0; i < K_; ++i) xx[i] = 0.f;
    }
#pragma unroll
    for (int ci = 0; ci < K_; ++ci) {
      float xs = xx[ci];
      const float* wr = sw + (ci * NTAP_B + t) * K_;
#pragma unroll
      for (int co = 0; co < K_; ++co) acc[co] = fmaf(xs, wr[co], acc[co]);
    }
  }
}

// ---------------------------------------------------------------- conv1 (24->24, relu)
__global__ __launch_bounds__(256, 4) void conv1_k(const float* __restrict__ src,
                                                  const float* __restrict__ wp,
                                                  const float* __restrict__ b,
                                                  float* __restrict__ dst) {
  __shared__ float sw[K_ * NTAP_B * K_];
  __shared__ float sb[K_];
  {
    const float4* wp4 = (const float4*)wp;
    float4* sw4 = (float4*)sw;
    for (int i = threadIdx.x; i < K_ * NTAP_B * K_ / 4; i += 256) sw4[i] = wp4[i];
    if (threadIdx.x < K_) sb[threadIdx.x] = b[threadIdx.x];
  }
  __syncthreads();

  int blk = blockIdx.x;
  int h2 = blk & 63;
  int d = (blk >> 6) & 15;
  int n = blk >> 10;
  int w = threadIdx.x & 127;
  int h = (h2 << 1) | (threadIdx.x >> 7);

  float acc[K_];
  conv14_acc(src, sw, sb, n, d, h, w, acc);

  float* dstp = dst + (size_t)(((n * D_ + d) * H_ + h) * W_ + w) * K_;
#pragma unroll
  for (int i = 0; i < K_; i += 4) {
    float4 v = make_float4(fmaxf(acc[i], 0.f), fmaxf(acc[i + 1], 0.f),
                           fmaxf(acc[i + 2], 0.f), fmaxf(acc[i + 3], 0.f));
    *(float4*)(dstp + i) = v;
  }
}

// ---------------------------------------------------------------- conv2 + residual + relu + logits + bitcost
__global__ __launch_bounds__(256, 4) void conv2_bc_k(
    const float* __restrict__ h1, const float* __restrict__ h0,
    const float* __restrict__ w2p, const float* __restrict__ b2,
    const float* __restrict__ w_out, const float* __restrict__ b_out,
    const int* __restrict__ tgt, float* __restrict__ bco) {
  __shared__ float sw[K_ * NTAP_B * K_];
  __shared__ float sb[K_];
  __shared__ float swo[L_ * K_];
  __shared__ float sbo[L_];
  {
    const float4* wp4 = (const float4*)w2p;
    float4* sw4 = (float4*)sw;
    for (int i = threadIdx.x; i < K_ * NTAP_B * K_ / 4; i += 256) sw4[i] = wp4[i];
    if (threadIdx.x < K_) sb[threadIdx.x] = b2[threadIdx.x];
    if (threadIdx.x < L_ * K_) swo[threadIdx.x] = w_out[threadIdx.x];
    if (threadIdx.x >= 128 && threadIdx.x < 128 + L_) sbo[threadIdx.x - 128] = b_out[threadIdx.x - 128];
  }
  __syncthreads();

  int blk = blockIdx.x;
  int h2 = blk & 63;
  int d = (blk >> 6) & 15;
  int n = blk >> 10;
  int w = threadIdx.x & 127;
  int h = (h2 << 1) | (threadIdx.x >> 7);

  float acc[K_];
  conv14_acc(h1, sw, sb, n, d, h, w, acc);

  size_t pos = (size_t)(((n * D_ + d) * H_ + h) * W_ + w);
  const float4* hp = (const float4*)(h0 + pos * K_);
#pragma unroll
  for (int i = 0; i < 6; ++i) {
    float4 v = hp[i];
    acc[4 * i]     = fmaxf(acc[4 * i]     + v.x, 0.f);
    acc[4 * i + 1] = fmaxf(acc[4 * i + 1] + v.y, 0.f);
    acc[4 * i + 2] = fmaxf(acc[4 * i + 2] + v.z, 0.f);
    acc[4 * i + 3] = fmaxf(acc[4 * i + 3] + v.w, 0.f);
  }

  float lg[L_];
#pragma unroll
  for (int l = 0; l < L_; ++l) lg[l] = sbo[l];
#pragma unroll
  for (int k = 0; k < K_; ++k) {
    float rv = acc[k];
#pragma unroll
    for (int l = 0; l < L_; ++l) lg[l] = fmaf(rv, swo[l * K_ + k], lg[l]);
  }

  float m = lg[0];
#pragma unroll
  for (int l = 1; l < L_; ++l) m = fmaxf(m, lg[l]);
  float s = 0.f;
#pragma unroll
  for (int l = 0; l < L_; ++l) s += expf(lg[l] - m);

  int t = tgt[pos];
  float lt = lg[0];
#pragma unroll
  for (int l = 1; l < L_; ++l) lt = (t == l) ? lg[l] : lt;

  float lp = lt - m - logf(s);
  float v = -lp / 0.69314718055994530942f;

  bco[((n * H_ + h) * W_ + w) * D_ + d] = v;  // NHWC (c = depth)
}

// ---------------------------------------------------------------- launch
extern "C" void kernel_launch(void* const* d_in, const int* in_sizes, int n_in,
                              void* d_out, int out_size, void* d_ws, size_t ws_size,
                              hipStream_t stream) {
  const float* x       = (const float*)d_in[0];
  const float* centers = (const float*)d_in[1];
  const float* w0      = (const float*)d_in[2];
  const float* b0      = (const float*)d_in[3];
  const float* w1      = (const float*)d_in[4];
  const float* b1      = (const float*)d_in[5];
  const float* w2      = (const float*)d_in[6];
  const float* b2      = (const float*)d_in[7];
  const float* w_out   = (const float*)d_in[8];
  const float* b_out   = (const float*)d_in[9];
  float* out = (float*)d_out;

  float* ws  = (float*)d_ws;
  float* q   = ws + OFF_Q;
  int*   tg  = (int*)(ws + OFF_TGT);
  float* h0  = ws + OFF_H0;
  float* h1  = ws + OFF_H1;
  float* w0p = ws + OFF_W0P;
  float* w1p = ws + OFF_W1P;
  float* w2p = ws + OFF_W2P;

  hipLaunchKernelGGL(pack_weights_k, dim3(1), dim3(256), 0, stream,
                     w0, w1, w2, w0p, w1p, w2p);
  hipLaunchKernelGGL(quantize_k, dim3(4096), dim3(256), 0, stream,
                     x, centers, out, q, tg);
  hipLaunchKernelGGL(conv0_k, dim3(4096), dim3(256), 0, stream,
                     q, w0p, b0, centers, h0);
  hipLaunchKernelGGL(conv1_k, dim3(4096), dim3(256), 0, stream,
                     h0, w1p, b1, h1);
  hipLaunchKernelGGL(conv2_bc_k, dim3(4096), dim3(256), 0, stream,
                     h1, h0, w2p, b2, w_out, b_out, tg, out + 1048576);
}

// Round 2
// 630.576 us; speedup vs baseline: 1.0545x; 1.0545x over previous
//
#include <hip/hip_runtime.h>
#include <cstddef>

#define N_ 4
#define D_ 16
#define H_ 128
#define W_ 128
#define K_ 24
#define L_ 6
#define NTAP_A 13
#define NTAP_B 14

// workspace layout (float offsets)
#define OFF_Q   0u
#define OFF_TGT 1048576u
#define OFF_H0  2097152u
#define OFF_H1  27262976u
#define OFF_W0P 52428800u
#define OFF_W1P 52429312u
#define OFF_W2P 52437376u

// ---------------------------------------------------------------- pack weights
// w1p/w2p layout: [t][ci][co]  (t outer so the runtime-uniform tap index gives
// a single scalar base; ci/co offsets are compile-time constants -> s_load)
__global__ void pack_weights_k(const float* __restrict__ w0,
                               const float* __restrict__ w1,
                               const float* __restrict__ w2,
                               float* __restrict__ w0p,
                               float* __restrict__ w1p,
                               float* __restrict__ w2p) {
  int tid = threadIdx.x;
  // w0: [24][1][27] -> w0p[t][co], t<13 (mask A: idx < 13)
  for (int i = tid; i < NTAP_A * K_; i += 256) {
    int co = i % K_;
    int t  = i / K_;
    w0p[t * K_ + co] = w0[co * 27 + t];
  }
  // w1/w2: [co=24][ci=24][27] -> wp[t][ci][co], t<14 (mask B: idx <= 13)
  for (int i = tid; i < K_ * NTAP_B * K_; i += 256) {
    int co = i % K_;
    int ci = (i / K_) % K_;
    int t  = i / (K_ * K_);
    w1p[i] = w1[(co * K_ + ci) * 27 + t];
    w2p[i] = w2[(co * K_ + ci) * 27 + t];
  }
}

// ---------------------------------------------------------------- quantize
__global__ __launch_bounds__(256) void quantize_k(
    const float* __restrict__ x, const float* __restrict__ centers,
    float* __restrict__ qbar_out, float* __restrict__ q,
    int* __restrict__ tgt) {
  int idx = blockIdx.x * 256 + threadIdx.x;  // over [n][c][h][w]
  int w = idx & 127;
  int h = (idx >> 7) & 127;
  int c = (idx >> 14) & 15;
  int n = idx >> 18;

  float cs[L_];
#pragma unroll
  for (int l = 0; l < L_; ++l) cs[l] = centers[l];

  int xi = ((n * H_ + h) * W_ + w) * D_ + c;  // NHWC
  float xv = x[xi];

  float dv[L_];
  float dmin = 3.4e38f;
  int sym = 0;
#pragma unroll
  for (int l = 0; l < L_; ++l) {
    float df = xv - cs[l];
    float d = df * df;
    dv[l] = d;
    if (d < dmin) { dmin = d; sym = l; }
  }
  float e[L_];
  float s = 0.f;
#pragma unroll
  for (int l = 0; l < L_; ++l) {
    e[l] = expf(dmin - dv[l]);
    s += e[l];
  }
  float qsoft = 0.f;
#pragma unroll
  for (int l = 0; l < L_; ++l) qsoft += (e[l] / s) * cs[l];

  float qhard = cs[sym];
  float qb = qsoft + (qhard - qsoft);

  qbar_out[xi] = qb;
  q[idx] = qb;  // [n][c(depth)][h][w]
  tgt[idx] = sym;
}

// ---------------------------------------------------------------- conv0 (1 -> 24, 13 taps, pad = centers[0])
__global__ __launch_bounds__(256) void conv0_k(
    const float* __restrict__ q, const float* __restrict__ w0p,
    const float* __restrict__ b0, const float* __restrict__ centers,
    float* __restrict__ h0) {
  float pv = centers[0];

  int blk = blockIdx.x;  // 4096 = 64 h-pairs * 16 d * 4 n
  int h2 = blk & 63;
  int d = __builtin_amdgcn_readfirstlane((blk >> 6) & 15);
  int n = __builtin_amdgcn_readfirstlane(blk >> 10);
  int w = threadIdx.x & 127;
  int h = __builtin_amdgcn_readfirstlane((h2 << 1) | (threadIdx.x >> 7));

  float acc[K_];
#pragma unroll
  for (int i = 0; i < K_; ++i) acc[i] = b0[i];  // uniform -> s_load

  const float* base = q + ((n * D_ + d) * H_ + h) * W_ + w;

#pragma unroll 1
  for (int t = 0; t < NTAP_A; ++t) {
    int dz = t / 9 - 1;
    int r = t % 9;
    int dy = r / 3 - 1;
    int dx = r % 3 - 1;
    int hh = h + dy, ww = w + dx, dd = d + dz;
    bool ok = (dd >= 0) && ((unsigned)hh < H_) && ((unsigned)ww < W_);
    float xv = ok ? base[(dz * H_ + dy) * W_ + dx] : pv;
    const float* wr = w0p + t * K_;  // uniform base, const offsets -> s_load
#pragma unroll
    for (int co = 0; co < K_; ++co) acc[co] = fmaf(xv, wr[co], acc[co]);
  }

  float* dst = h0 + (size_t)(((n * D_ + d) * H_ + h) * W_ + w) * K_;
#pragma unroll
  for (int i = 0; i < K_; i += 4) {
    float4 v = make_float4(fmaxf(acc[i], 0.f), fmaxf(acc[i + 1], 0.f),
                           fmaxf(acc[i + 2], 0.f), fmaxf(acc[i + 3], 0.f));
    *(float4*)(dst + i) = v;
  }
}

// ---------------------------------------------------------------- 24->24 masked-B conv accumulate (14 taps)
// Weights read straight from global with wave-uniform addresses -> SMEM
// (s_load) path; v_fma takes the SGPR operand for free. No LDS at all.
__device__ __forceinline__ void conv14_acc(const float* __restrict__ src,
                                           const float* __restrict__ wp,
                                           const float* __restrict__ b,
                                           int n, int d, int h, int w,
                                           float acc[K_]) {
#pragma unroll
  for (int i = 0; i < K_; ++i) acc[i] = b[i];  // uniform -> s_load

  const float* base = src + (size_t)(((n * D_ + d) * H_ + h) * W_ + w) * K_;

#pragma unroll 1
  for (int t = 0; t < NTAP_B; ++t) {
    int dz = t / 9 - 1;
    int r = t % 9;
    int dy = r / 3 - 1;
    int dx = r % 3 - 1;
    int hh = h + dy, ww = w + dx, dd = d + dz;
    bool ok = (dd >= 0) && ((unsigned)hh < H_) && ((unsigned)ww < W_);
    const float4* p =
        (const float4*)(base + (ptrdiff_t)((dz * H_ + dy) * W_ + dx) * K_);
    float xx[K_];
    if (ok) {
#pragma unroll
      for (int i = 0; i < 6; ++i) {
        float4 v = p[i];
        xx[4 * i] = v.x; xx[4 * i + 1] = v.y; xx[4 * i + 2] = v.z; xx[4 * i + 3] = v.w;
      }
    } else {
#pragma unroll
      for (int i = 0; i < K_; ++i) xx[i] = 0.f;
    }
    const float* wt = wp + t * (K_ * K_);  // uniform runtime base
#pragma unroll
    for (int ci = 0; ci < K_; ++ci) {
      float xs = xx[ci];
      const float* wr = wt + ci * K_;      // const offsets -> s_load_dwordx
#pragma unroll
      for (int co = 0; co < K_; ++co) acc[co] = fmaf(xs, wr[co], acc[co]);
    }
  }
}

// ---------------------------------------------------------------- conv1 (24->24, relu)
__global__ __launch_bounds__(256, 4) void conv1_k(const float* __restrict__ src,
                                                  const float* __restrict__ wp,
                                                  const float* __restrict__ b,
                                                  float* __restrict__ dst) {
  int blk = blockIdx.x;
  int h2 = blk & 63;
  int d = __builtin_amdgcn_readfirstlane((blk >> 6) & 15);
  int n = __builtin_amdgcn_readfirstlane(blk >> 10);
  int w = threadIdx.x & 127;
  int h = __builtin_amdgcn_readfirstlane((h2 << 1) | (threadIdx.x >> 7));

  float acc[K_];
  conv14_acc(src, wp, b, n, d, h, w, acc);

  float* dstp = dst + (size_t)(((n * D_ + d) * H_ + h) * W_ + w) * K_;
#pragma unroll
  for (int i = 0; i < K_; i += 4) {
    float4 v = make_float4(fmaxf(acc[i], 0.f), fmaxf(acc[i + 1], 0.f),
                           fmaxf(acc[i + 2], 0.f), fmaxf(acc[i + 3], 0.f));
    *(float4*)(dstp + i) = v;
  }
}

// ---------------------------------------------------------------- conv2 + residual + relu + logits + bitcost
__global__ __launch_bounds__(256, 4) void conv2_bc_k(
    const float* __restrict__ h1, const float* __restrict__ h0,
    const float* __restrict__ w2p, const float* __restrict__ b2,
    const float* __restrict__ w_out, const float* __restrict__ b_out,
    const int* __restrict__ tgt, float* __restrict__ bco) {
  int blk = blockIdx.x;
  int h2 = blk & 63;
  int d = __builtin_amdgcn_readfirstlane((blk >> 6) & 15);
  int n = __builtin_amdgcn_readfirstlane(blk >> 10);
  int w = threadIdx.x & 127;
  int h = __builtin_amdgcn_readfirstlane((h2 << 1) | (threadIdx.x >> 7));

  float acc[K_];
  conv14_acc(h1, w2p, b2, n, d, h, w, acc);

  size_t pos = (size_t)(((n * D_ + d) * H_ + h) * W_ + w);
  const float4* hp = (const float4*)(h0 + pos * K_);
#pragma unroll
  for (int i = 0; i < 6; ++i) {
    float4 v = hp[i];
    acc[4 * i]     = fmaxf(acc[4 * i]     + v.x, 0.f);
    acc[4 * i + 1] = fmaxf(acc[4 * i + 1] + v.y, 0.f);
    acc[4 * i + 2] = fmaxf(acc[4 * i + 2] + v.z, 0.f);
    acc[4 * i + 3] = fmaxf(acc[4 * i + 3] + v.w, 0.f);
  }

  float lg[L_];
#pragma unroll
  for (int l = 0; l < L_; ++l) lg[l] = b_out[l];  // uniform -> s_load
#pragma unroll
  for (int k = 0; k < K_; ++k) {
    float rv = acc[k];
#pragma unroll
    for (int l = 0; l < L_; ++l) lg[l] = fmaf(rv, w_out[l * K_ + k], lg[l]);
  }

  float m = lg[0];
#pragma unroll
  for (int l = 1; l < L_; ++l) m = fmaxf(m, lg[l]);
  float s = 0.f;
#pragma unroll
  for (int l = 0; l < L_; ++l) s += expf(lg[l] - m);

  int t = tgt[pos];
  float lt = lg[0];
#pragma unroll
  for (int l = 1; l < L_; ++l) lt = (t == l) ? lg[l] : lt;

  float lp = lt - m - logf(s);
  float v = -lp / 0.69314718055994530942f;

  bco[((n * H_ + h) * W_ + w) * D_ + d] = v;  // NHWC (c = depth)
}

// ---------------------------------------------------------------- launch
extern "C" void kernel_launch(void* const* d_in, const int* in_sizes, int n_in,
                              void* d_out, int out_size, void* d_ws, size_t ws_size,
                              hipStream_t stream) {
  const float* x       = (const float*)d_in[0];
  const float* centers = (const float*)d_in[1];
  const float* w0      = (const float*)d_in[2];
  const float* b0      = (const float*)d_in[3];
  const float* w1      = (const float*)d_in[4];
  const float* b1      = (const float*)d_in[5];
  const float* w2      = (const float*)d_in[6];
  const float* b2      = (const float*)d_in[7];
  const float* w_out   = (const float*)d_in[8];
  const float* b_out   = (const float*)d_in[9];
  float* out = (float*)d_out;

  float* ws  = (float*)d_ws;
  float* q   = ws + OFF_Q;
  int*   tg  = (int*)(ws + OFF_TGT);
  float* h0  = ws + OFF_H0;
  float* h1  = ws + OFF_H1;
  float* w0p = ws + OFF_W0P;
  float* w1p = ws + OFF_W1P;
  float* w2p = ws + OFF_W2P;

  hipLaunchKernelGGL(pack_weights_k, dim3(1), dim3(256), 0, stream,
                     w0, w1, w2, w0p, w1p, w2p);
  hipLaunchKernelGGL(quantize_k, dim3(4096), dim3(256), 0, stream,
                     x, centers, out, q, tg);
  hipLaunchKernelGGL(conv0_k, dim3(4096), dim3(256), 0, stream,
                     q, w0p, b0, centers, h0);
  hipLaunchKernelGGL(conv1_k, dim3(4096), dim3(256), 0, stream,
                     h0, w1p, b1, h1);
  hipLaunchKernelGGL(conv2_bc_k, dim3(4096), dim3(256), 0, stream,
                     h1, h0, w2p, b2, w_out, b_out, tg, out + 1048576);
}